// Round 3
// baseline (1087.510 us; speedup 1.0000x reference)
//
#include <hip/hip_runtime.h>
#include <hip/hip_bf16.h>

typedef __hip_bfloat16 bf16;
typedef __bf16 bf16x8 __attribute__((ext_vector_type(8)));
typedef __bf16 bf16x4 __attribute__((ext_vector_type(4)));
typedef float f32x4 __attribute__((ext_vector_type(4)));

#define DN_ 256
#define DE_ 64
#define DM_ 256
#define DX_ 256
#define LDA1 264   // padded LDS stride (bf16 elems) for K=256 tiles
#define LDA2 72    // padded LDS stride for K=64 tiles
#define CAP 32     // incoming-edge bucket capacity (Poisson mean 3; P(deg>32) ~ 1e-24)

// Workspace plan (big path): base2 153.6 + msg/fnodeb(alias) 153.6 + cnt 0.4
//   + slot 12.8 + inv 1.2 + alpha3 5.12 + weights 0.56 + m3/agg(alias) 153.6
//   = 480.9 MB. If ws_size is smaller, fall back to the verified R2 schedule
//   (base2 + msg + agg = 378.5 MB, k_aggregate/k_update path).

static __device__ __forceinline__ bf16 f2b(float x) { return __float2bfloat16(x); }
static __device__ __forceinline__ float us2f(unsigned short u) {
    return __uint_as_float((unsigned)u << 16);
}

union U16x8 { uint4 u; unsigned short s[8]; };

static __device__ __forceinline__ f32x4 mfma16(bf16x8 a, bf16x8 b, f32x4 c) {
    return __builtin_amdgcn_mfma_f32_16x16x32_bf16(a, b, c, 0, 0, 0);
}

// 64x256 output tile GEMM: acc += T(64xK in LDS, bf16) @ WT (bf16, transposed: WT[n*K+k]).
// 4 waves: wave w owns cols [64w, 64w+64).
// SWAPPED operand order: mfma(b, a, acc) ->
//   value(lane, reg rr) = out[i*16 + (lane&15)][w*64 + j*16 + (lane>>4)*4 + rr]
// i.e. each lane holds 4 CONSECUTIVE COLUMNS of one row -> vectorized epilogues.
template <int LDA, int KTOT>
static __device__ __forceinline__ void gemm_acc(const bf16* T, const bf16* WT,
                                                f32x4 acc[4][4], int lane, int wave) {
    const int m = lane & 15, quad = lane >> 4;
#pragma unroll
    for (int k0 = 0; k0 < KTOT; k0 += 32) {
        bf16x8 a[4], b[4];
#pragma unroll
        for (int i = 0; i < 4; ++i)
            a[i] = *(const bf16x8*)&T[(i * 16 + m) * LDA + k0 + quad * 8];
#pragma unroll
        for (int j = 0; j < 4; ++j) {
            int n = wave * 64 + j * 16 + m;
            b[j] = *(const bf16x8*)&WT[(size_t)n * KTOT + k0 + quad * 8];
        }
#pragma unroll
        for (int i = 0; i < 4; ++i)
#pragma unroll
            for (int j = 0; j < 4; ++j)
                acc[i][j] = mfma16(b[j], a[i], acc[i][j]);
    }
}

// W (f32, K x NC row-major) -> WT (bf16, NC x K)
__global__ void __launch_bounds__(256) k_transpose(const float* __restrict__ W,
                                                   bf16* __restrict__ WT, int K, int NC) {
    int i = blockIdx.x * 256 + threadIdx.x;
    if (i < K * NC) {
        int k = i / NC, n = i % NC;
        WT[n * K + k] = f2b(W[i]);
    }
}

// f32 -> bf16 bulk convert (8 elems/thread)
__global__ void __launch_bounds__(256) k_cvt(const float* __restrict__ in,
                                             bf16* __restrict__ out, long total) {
    long i = ((long)blockIdx.x * 256 + threadIdx.x) * 8;
    if (i >= total) return;
    float4 v0 = *(const float4*)(in + i);
    float4 v1 = *(const float4*)(in + i + 4);
    bf16x8 b = {(__bf16)v0.x, (__bf16)v0.y, (__bf16)v0.z, (__bf16)v0.w,
                (__bf16)v1.x, (__bf16)v1.y, (__bf16)v1.z, (__bf16)v1.w};
    *(bf16x8*)(out + i) = b;
}

// incoming-edge buckets: slot[d*CAP + pos] = e for each e with edst[e]==d
__global__ void __launch_bounds__(256) k_bucket(const int* __restrict__ edst,
                                                int* __restrict__ cnt,
                                                int* __restrict__ slot, int E) {
    int e = blockIdx.x * 256 + threadIdx.x;
    if (e < E) {
        int d = edst[e];
        int pos = atomicAdd(&cnt[d], 1);
        if (pos < CAP) slot[(size_t)d * CAP + pos] = e;
    }
}

// inv[tgt[r]] = r  (inv pre-memset to -1)
__global__ void __launch_bounds__(256) k_invset(const int* __restrict__ tgt,
                                                int* __restrict__ inv, int M) {
    int r = blockIdx.x * 256 + threadIdx.x;
    if (r < M) inv[tgt[r]] = r;
}

// agg[n] = sum over incoming edges of msg rows (f32 accumulate, bf16 store).
__global__ void __launch_bounds__(256) k_aggregate(const bf16* __restrict__ msg,
                                                   const int* __restrict__ cnt,
                                                   const int* __restrict__ slot,
                                                   bf16* __restrict__ agg, int N,
                                                   int relu_in) {
    int wid = (blockIdx.x * 256 + threadIdx.x) >> 6;  // node id
    int lane = threadIdx.x & 63;
    if (wid >= N) return;
    int c = cnt[wid];
    if (c > CAP) c = CAP;
    const int* sp = slot + (size_t)wid * CAP;
    float a0 = 0.f, a1 = 0.f, a2 = 0.f, a3 = 0.f;
    if (relu_in) {
        for (int i = 0; i < c; ++i) {
            int e = sp[i];
            ushort4 mv = *(const ushort4*)((const unsigned short*)msg + (size_t)e * DM_ + lane * 4);
            a0 += fmaxf(us2f(mv.x), 0.f); a1 += fmaxf(us2f(mv.y), 0.f);
            a2 += fmaxf(us2f(mv.z), 0.f); a3 += fmaxf(us2f(mv.w), 0.f);
        }
    } else {
        for (int i = 0; i < c; ++i) {
            int e = sp[i];
            ushort4 mv = *(const ushort4*)((const unsigned short*)msg + (size_t)e * DM_ + lane * 4);
            a0 += us2f(mv.x); a1 += us2f(mv.y); a2 += us2f(mv.z); a3 += us2f(mv.w);
        }
    }
    bf16x4 o = {(__bf16)a0, (__bf16)a1, (__bf16)a2, (__bf16)a3};
    *(bf16x4*)(agg + (size_t)wid * DM_ + lane * 4) = o;
}

// alpha3[r] = tree_msg[r] @ W3   (compact [M, DM] bf16 output)
__global__ void __launch_bounds__(256) k_alpha(const float* __restrict__ tm,
                                               const bf16* __restrict__ W3T,
                                               bf16* __restrict__ alpha3, int M) {
    __shared__ bf16 T[64 * LDA1];
    const int tile0 = blockIdx.x * 64, tid = threadIdx.x;
#pragma unroll
    for (int it = 0; it < 16; ++it) {
        int c = tid + it * 256;
        int r = c >> 6, cc = c & 63;
        int row = tile0 + r;
        if (row >= M) row = 0;
        float4 v = *(const float4*)(tm + (size_t)row * DM_ + cc * 4);
        bf16x4 b = {(__bf16)v.x, (__bf16)v.y, (__bf16)v.z, (__bf16)v.w};
        *(bf16x4*)&T[r * LDA1 + cc * 4] = b;
    }
    __syncthreads();
    const int lane = tid & 63, wave = tid >> 6;
    const int m = lane & 15, quad = lane >> 4;
    f32x4 acc[4][4];
#pragma unroll
    for (int i = 0; i < 4; ++i)
#pragma unroll
        for (int j = 0; j < 4; ++j) acc[i][j] = (f32x4){0.f, 0.f, 0.f, 0.f};
    gemm_acc<LDA1, 256>(T, W3T, acc, lane, wave);
#pragma unroll
    for (int i = 0; i < 4; ++i) {
        int row = tile0 + i * 16 + m;
        if (row < M) {
            size_t rb = (size_t)row * DM_;
#pragma unroll
            for (int j = 0; j < 4; ++j) {
                int c0 = wave * 64 + j * 16 + quad * 4;
                bf16x4 o = {(__bf16)acc[i][j][0], (__bf16)acc[i][j][1],
                            (__bf16)acc[i][j][2], (__bf16)acc[i][j][3]};
                *(bf16x4*)(alpha3 + rb + c0) = o;
            }
        }
    }
}

// base2 = f_node_bf16[src] @ W1 + f_edge @ W2 + b1 (+ alpha3[inv[e]] where inv>=0)
__global__ void __launch_bounds__(256) k_base(const bf16* __restrict__ fnb,
                                              const float* __restrict__ fedge,
                                              const int* __restrict__ esrc,
                                              const bf16* __restrict__ W1T,
                                              const bf16* __restrict__ W2T,
                                              const float* __restrict__ b1,
                                              const int* __restrict__ inv,
                                              const bf16* __restrict__ alpha3,
                                              bf16* __restrict__ base2, int E) {
    __shared__ bf16 T[64 * LDA1];
    const int tile0 = blockIdx.x * 64, tid = threadIdx.x;
    // stage gathered bf16 f_node rows: pure 16B copies (64 rows x 32 chunks)
#pragma unroll
    for (int it = 0; it < 8; ++it) {
        int c = tid + it * 256;
        int r = c >> 5, cc = c & 31;
        int e = tile0 + r;
        if (e >= E) e = 0;
        int s = esrc[e];
        *(uint4*)&T[r * LDA1 + cc * 8] =
            *(const uint4*)((const unsigned short*)fnb + (size_t)s * DN_ + cc * 8);
    }
    __syncthreads();
    const int lane = tid & 63, wave = tid >> 6;
    const int m = lane & 15, quad = lane >> 4;
    f32x4 acc[4][4];
#pragma unroll
    for (int i = 0; i < 4; ++i)
#pragma unroll
        for (int j = 0; j < 4; ++j) acc[i][j] = (f32x4){0.f, 0.f, 0.f, 0.f};
    gemm_acc<LDA1, 256>(T, W1T, acc, lane, wave);
    __syncthreads();
    // stage contiguous f_edge rows (64 x 64, f32 -> bf16)
#pragma unroll
    for (int it = 0; it < 4; ++it) {
        int c = tid + it * 256;
        int r = c >> 4, cc = c & 15;
        int e = tile0 + r;
        if (e >= E) e = 0;
        float4 v = *(const float4*)(fedge + (size_t)e * DE_ + cc * 4);
        bf16x4 b = {(__bf16)v.x, (__bf16)v.y, (__bf16)v.z, (__bf16)v.w};
        *(bf16x4*)&T[r * LDA2 + cc * 4] = b;
    }
    __syncthreads();
    gemm_acc<LDA2, 64>(T, W2T, acc, lane, wave);
    // vectorized epilogue: each lane owns 4 consecutive cols of row (i*16+m)
    float4 bj[4];
#pragma unroll
    for (int j = 0; j < 4; ++j)
        bj[j] = *(const float4*)&b1[wave * 64 + j * 16 + quad * 4];
#pragma unroll
    for (int i = 0; i < 4; ++i) {
        int e = tile0 + i * 16 + m;
        if (e < E) {
            int iv = inv[e];
            size_t rb = (size_t)e * DM_;
#pragma unroll
            for (int j = 0; j < 4; ++j) {
                int c0 = wave * 64 + j * 16 + quad * 4;
                float v0 = acc[i][j][0] + bj[j].x;
                float v1 = acc[i][j][1] + bj[j].y;
                float v2 = acc[i][j][2] + bj[j].z;
                float v3 = acc[i][j][3] + bj[j].w;
                if (iv >= 0) {
                    ushort4 al = *(const ushort4*)((const unsigned short*)alpha3 +
                                                   (size_t)iv * DM_ + c0);
                    v0 += us2f(al.x); v1 += us2f(al.y);
                    v2 += us2f(al.z); v3 += us2f(al.w);
                }
                bf16x4 o = {(__bf16)v0, (__bf16)v1, (__bf16)v2, (__bf16)v3};
                *(bf16x4*)(base2 + rb + c0) = o;
            }
        }
    }
}

// m3 = (relu_in ? relu(src) : src) @ W3 -- pure streaming GEMM, contiguous rows
__global__ void __launch_bounds__(256) k_gemm3(const bf16* __restrict__ src,
                                               const bf16* __restrict__ W3T,
                                               bf16* __restrict__ m3, int E,
                                               int relu_in) {
    __shared__ bf16 T[64 * LDA1];
    const int tile0 = blockIdx.x * 64, tid = threadIdx.x;
#pragma unroll
    for (int it = 0; it < 8; ++it) {
        int c = tid + it * 256;
        int r = c >> 5, cc = c & 31;
        int e = tile0 + r;
        if (e >= E) e = 0;
        U16x8 v;
        v.u = *(const uint4*)((const unsigned short*)src + (size_t)e * DM_ + cc * 8);
        if (relu_in) {
#pragma unroll
            for (int t = 0; t < 8; ++t)
                if ((short)v.s[t] < 0) v.s[t] = 0;  // bf16 relu via sign bit
        }
        *(uint4*)&T[r * LDA1 + cc * 8] = v.u;
    }
    __syncthreads();
    const int lane = tid & 63, wave = tid >> 6;
    const int m = lane & 15, quad = lane >> 4;
    f32x4 acc[4][4];
#pragma unroll
    for (int i = 0; i < 4; ++i)
#pragma unroll
        for (int j = 0; j < 4; ++j) acc[i][j] = (f32x4){0.f, 0.f, 0.f, 0.f};
    gemm_acc<LDA1, 256>(T, W3T, acc, lane, wave);
#pragma unroll
    for (int i = 0; i < 4; ++i) {
        int e = tile0 + i * 16 + m;
        if (e < E) {
            size_t rb = (size_t)e * DM_;
#pragma unroll
            for (int j = 0; j < 4; ++j) {
                int c0 = wave * 64 + j * 16 + quad * 4;
                bf16x4 o = {(__bf16)acc[i][j][0], (__bf16)acc[i][j][1],
                            (__bf16)acc[i][j][2], (__bf16)acc[i][j][3]};
                *(bf16x4*)(m3 + rb + c0) = o;
            }
        }
    }
}

// Per node u (one wave): agg3 = sum of m3 over incoming edges er; then for each
// er: msg[er^1] = relu(base2[er^1] + agg3 - m3[er]).
// (incoming edges of u are exactly the reverses of u's outgoing edges, so this
//  produces every outgoing message of u; every edge is outgoing of its src.)
__global__ void __launch_bounds__(256) k_fuse(const bf16* __restrict__ m3,
                                              const bf16* __restrict__ base2,
                                              const int* __restrict__ cnt,
                                              const int* __restrict__ slot,
                                              bf16* __restrict__ msg, int N) {
    int wid = (blockIdx.x * 256 + threadIdx.x) >> 6;  // node id
    int lane = threadIdx.x & 63;
    if (wid >= N) return;
    int c = cnt[wid];
    if (c > CAP) c = CAP;
    const int* sp = slot + (size_t)wid * CAP;
    float a0 = 0.f, a1 = 0.f, a2 = 0.f, a3 = 0.f;
    for (int i = 0; i < c; ++i) {
        int er = sp[i];
        ushort4 mv = *(const ushort4*)((const unsigned short*)m3 + (size_t)er * DM_ + lane * 4);
        a0 += us2f(mv.x); a1 += us2f(mv.y); a2 += us2f(mv.z); a3 += us2f(mv.w);
    }
    for (int i = 0; i < c; ++i) {
        int er = sp[i];
        int e = er ^ 1;
        ushort4 mv = *(const ushort4*)((const unsigned short*)m3 + (size_t)er * DM_ + lane * 4);
        ushort4 bv = *(const ushort4*)((const unsigned short*)base2 + (size_t)e * DM_ + lane * 4);
        float v0 = fmaxf(us2f(bv.x) + a0 - us2f(mv.x), 0.f);
        float v1 = fmaxf(us2f(bv.y) + a1 - us2f(mv.y), 0.f);
        float v2 = fmaxf(us2f(bv.z) + a2 - us2f(mv.z), 0.f);
        float v3 = fmaxf(us2f(bv.w) + a3 - us2f(mv.w), 0.f);
        bf16x4 o = {(__bf16)v0, (__bf16)v1, (__bf16)v2, (__bf16)v3};
        *(bf16x4*)(msg + (size_t)e * DM_ + lane * 4) = o;
    }
}

// msgout = relu(base2 + (agg[src] - msgin[rev]) @ W3)   [FALLBACK path only]
__global__ void __launch_bounds__(256) k_update(const bf16* __restrict__ agg,
                                                const bf16* __restrict__ base2,
                                                const int* __restrict__ esrc,
                                                const bf16* __restrict__ W3T,
                                                const bf16* __restrict__ msgin,
                                                bf16* __restrict__ msgout, int E,
                                                int relu_in) {
    __shared__ bf16 T[64 * LDA1];
    const int tile0 = blockIdx.x * 64, tid = threadIdx.x;
#pragma unroll
    for (int it = 0; it < 8; ++it) {
        int c = tid + it * 256;
        int r = c >> 5, cc = c & 31;
        int e = tile0 + r;
        int ec = e < E ? e : 0;
        int s = esrc[ec];
        int erev = tile0 + (r ^ 1);
        if (erev >= E) erev = 0;
        U16x8 av, mv;
        av.u = *(const uint4*)((const unsigned short*)agg + (size_t)s * DM_ + cc * 8);
        mv.u = *(const uint4*)((const unsigned short*)msgin + (size_t)erev * DM_ + cc * 8);
        bf16x8 o;
#pragma unroll
        for (int t = 0; t < 8; ++t) {
            float fm = us2f(mv.s[t]);
            if (relu_in) fm = fmaxf(fm, 0.f);
            o[t] = (__bf16)(us2f(av.s[t]) - fm);
        }
        *(bf16x8*)&T[r * LDA1 + cc * 8] = o;
    }
    __syncthreads();
    const int lane = tid & 63, wave = tid >> 6;
    const int m = lane & 15, quad = lane >> 4;
    f32x4 acc[4][4];
#pragma unroll
    for (int i = 0; i < 4; ++i)
#pragma unroll
        for (int j = 0; j < 4; ++j) acc[i][j] = (f32x4){0.f, 0.f, 0.f, 0.f};
    gemm_acc<LDA1, 256>(T, W3T, acc, lane, wave);
#pragma unroll
    for (int i = 0; i < 4; ++i) {
        int e = tile0 + i * 16 + m;
        if (e < E) {
            size_t rb = (size_t)e * DM_;
#pragma unroll
            for (int j = 0; j < 4; ++j) {
                int c0 = wave * 64 + j * 16 + quad * 4;
                ushort4 bv = *(const ushort4*)((const unsigned short*)base2 + rb + c0);
                float v0 = fmaxf(acc[i][j][0] + us2f(bv.x), 0.f);
                float v1 = fmaxf(acc[i][j][1] + us2f(bv.y), 0.f);
                float v2 = fmaxf(acc[i][j][2] + us2f(bv.z), 0.f);
                float v3 = fmaxf(acc[i][j][3] + us2f(bv.w), 0.f);
                bf16x4 o = {(__bf16)v0, (__bf16)v1, (__bf16)v2, (__bf16)v3};
                *(bf16x4*)(msgout + rb + c0) = o;
            }
        }
    }
}

// x = relu(f_node @ W4 + agg @ W5 + b2)   (f32 output, float4 stores)
__global__ void __launch_bounds__(256) k_readout(const float* __restrict__ fnode,
                                                 const bf16* __restrict__ agg,
                                                 const bf16* __restrict__ W4T,
                                                 const bf16* __restrict__ W5T,
                                                 const float* __restrict__ b2,
                                                 float* __restrict__ out, int N) {
    __shared__ bf16 T[64 * LDA1];
    const int tile0 = blockIdx.x * 64, tid = threadIdx.x;
#pragma unroll
    for (int it = 0; it < 16; ++it) {
        int c = tid + it * 256;
        int r = c >> 6, cc = c & 63;
        int n = tile0 + r;
        if (n >= N) n = 0;
        float4 v = *(const float4*)(fnode + (size_t)n * DN_ + cc * 4);
        bf16x4 b = {(__bf16)v.x, (__bf16)v.y, (__bf16)v.z, (__bf16)v.w};
        *(bf16x4*)&T[r * LDA1 + cc * 4] = b;
    }
    __syncthreads();
    const int lane = tid & 63, wave = tid >> 6;
    const int m = lane & 15, quad = lane >> 4;
    f32x4 acc[4][4];
#pragma unroll
    for (int i = 0; i < 4; ++i)
#pragma unroll
        for (int j = 0; j < 4; ++j) acc[i][j] = (f32x4){0.f, 0.f, 0.f, 0.f};
    gemm_acc<LDA1, 256>(T, W4T, acc, lane, wave);
    __syncthreads();
    // stage agg rows (already bf16): 64 rows x 32 x 16B
#pragma unroll
    for (int it = 0; it < 8; ++it) {
        int c = tid + it * 256;
        int r = c >> 5, cc = c & 31;
        int n = tile0 + r;
        if (n >= N) n = 0;
        *(uint4*)&T[r * LDA1 + cc * 8] =
            *(const uint4*)((const unsigned short*)agg + (size_t)n * DM_ + cc * 8);
    }
    __syncthreads();
    gemm_acc<LDA1, 256>(T, W5T, acc, lane, wave);
    float4 bj[4];
#pragma unroll
    for (int j = 0; j < 4; ++j)
        bj[j] = *(const float4*)&b2[wave * 64 + j * 16 + quad * 4];
#pragma unroll
    for (int i = 0; i < 4; ++i) {
        int n = tile0 + i * 16 + m;
        if (n < N) {
            size_t rb = (size_t)n * DX_;
#pragma unroll
            for (int j = 0; j < 4; ++j) {
                int c0 = wave * 64 + j * 16 + quad * 4;
                float4 o;
                o.x = fmaxf(acc[i][j][0] + bj[j].x, 0.f);
                o.y = fmaxf(acc[i][j][1] + bj[j].y, 0.f);
                o.z = fmaxf(acc[i][j][2] + bj[j].z, 0.f);
                o.w = fmaxf(acc[i][j][3] + bj[j].w, 0.f);
                *(float4*)(out + rb + c0) = o;
            }
        }
    }
}

extern "C" void kernel_launch(void* const* d_in, const int* in_sizes, int n_in,
                              void* d_out, int out_size, void* d_ws, size_t ws_size,
                              hipStream_t stream) {
    const float* f_node   = (const float*)d_in[0];
    const float* f_edge   = (const float*)d_in[1];
    const float* tree_msg = (const float*)d_in[2];
    const float* W1 = (const float*)d_in[3];
    const float* W2 = (const float*)d_in[4];
    const float* W3 = (const float*)d_in[5];
    const float* b1 = (const float*)d_in[6];
    const float* W4 = (const float*)d_in[7];
    const float* W5 = (const float*)d_in[8];
    const float* b2 = (const float*)d_in[9];
    const int* edge_src = (const int*)d_in[10];
    const int* edge_dst = (const int*)d_in[11];
    const int* tree_tgt = (const int*)d_in[12];

    const int N = in_sizes[0] / DN_;
    const int E = in_sizes[1] / DE_;
    const int M = in_sizes[2] / DM_;

    const size_t EB = (size_t)E * DM_ * 2;   // one E x DM bf16 buffer
    const size_t NB = (size_t)N * DM_ * 2;

    char* ws = (char*)d_ws;
    size_t off = 0;
    bf16* base2 = (bf16*)(ws + off); off += EB;
    bf16* msg   = (bf16*)(ws + off); off += EB;
    int* cnt    = (int*)(ws + off);   off += (size_t)N * 4;
    int* slot   = (int*)(ws + off);   off += (size_t)N * CAP * 4;
    int* inv    = (int*)(ws + off);   off += (size_t)E * 4;
    bf16* alpha3 = (bf16*)(ws + off); off += (size_t)M * DM_ * 2;
    bf16* W1T = (bf16*)(ws + off); off += 256 * 256 * 2;
    bf16* W2T = (bf16*)(ws + off); off += 256 * 64 * 2;
    bf16* W3T = (bf16*)(ws + off); off += 256 * 256 * 2;
    bf16* W4T = (bf16*)(ws + off); off += 256 * 256 * 2;
    bf16* W5T = (bf16*)(ws + off); off += 256 * 256 * 2;
    // tail region: big path gets m3 (EB, agg aliases it); fallback gets agg (NB)
    const int big = (ws_size - off) >= EB;
    bf16* m3  = (bf16*)(ws + off);
    bf16* agg = (bf16*)(ws + off);   // big: aliases m3 (m3 dead before final agg)
    bf16* fnb = msg;  // alias: f_node bf16 lives in msg buffer until msg first write

    k_transpose<<<(256 * 256 + 255) / 256, 256, 0, stream>>>(W1, W1T, 256, 256);
    k_transpose<<<(64 * 256 + 255) / 256, 256, 0, stream>>>(W2, W2T, 64, 256);
    k_transpose<<<(256 * 256 + 255) / 256, 256, 0, stream>>>(W3, W3T, 256, 256);
    k_transpose<<<(256 * 256 + 255) / 256, 256, 0, stream>>>(W4, W4T, 256, 256);
    k_transpose<<<(256 * 256 + 255) / 256, 256, 0, stream>>>(W5, W5T, 256, 256);

    // one-time CSR-bucket + inverse-alpha map for the (static) graph
    hipMemsetAsync(cnt, 0, (size_t)N * 4, stream);
    hipMemsetAsync(inv, 0xFF, (size_t)E * 4, stream);
    k_bucket<<<(E + 255) / 256, 256, 0, stream>>>(edge_dst, cnt, slot, E);
    k_invset<<<(M + 255) / 256, 256, 0, stream>>>(tree_tgt, inv, M);

    // bf16 copy of f_node (into msg alias) for the edge gather
    k_cvt<<<(int)(((size_t)N * DN_ / 8 + 255) / 256), 256, 0, stream>>>(
        f_node, fnb, (long)N * DN_);

    k_alpha<<<(M + 63) / 64, 256, 0, stream>>>(tree_msg, W3T, alpha3, M);
    k_base<<<(E + 63) / 64, 256, 0, stream>>>(fnb, f_edge, edge_src, W1T, W2T, b1,
                                              inv, alpha3, base2, E);
    // ITERS=3; msg_1 = relu(base2) is virtual, never materialized
    if (big) {
        // iteration 2: m3_1 = relu(base2)@W3; msg_2 = relu(base2 + agg3 - m3_1[rev])
        k_gemm3<<<(E + 63) / 64, 256, 0, stream>>>(base2, W3T, m3, E, 1);
        k_fuse<<<(N + 3) / 4, 256, 0, stream>>>(m3, base2, cnt, slot, msg, N);
        // iteration 3
        k_gemm3<<<(E + 63) / 64, 256, 0, stream>>>(msg, W3T, m3, E, 0);
        k_fuse<<<(N + 3) / 4, 256, 0, stream>>>(m3, base2, cnt, slot, msg, N);
    } else {
        // verified R2 fallback
        k_aggregate<<<(N + 3) / 4, 256, 0, stream>>>(base2, cnt, slot, agg, N, 1);
        k_update<<<(E + 63) / 64, 256, 0, stream>>>(agg, base2, edge_src, W3T,
                                                    base2, msg, E, 1);
        k_aggregate<<<(N + 3) / 4, 256, 0, stream>>>(msg, cnt, slot, agg, N, 0);
        k_update<<<(E + 63) / 64, 256, 0, stream>>>(agg, base2, edge_src, W3T,
                                                    msg, msg, E, 0);
    }
    k_aggregate<<<(N + 3) / 4, 256, 0, stream>>>(msg, cnt, slot, agg, N, 0);
    k_readout<<<(N + 63) / 64, 256, 0, stream>>>(f_node, agg, W4T, W5T, b2,
                                                 (float*)d_out, N);
}

// Round 4
// 1085.144 us; speedup vs baseline: 1.0022x; 1.0022x over previous
//
#include <hip/hip_runtime.h>
#include <hip/hip_bf16.h>

typedef __hip_bfloat16 bf16;
typedef __bf16 bf16x8 __attribute__((ext_vector_type(8)));
typedef __bf16 bf16x4 __attribute__((ext_vector_type(4)));
typedef float f32x4 __attribute__((ext_vector_type(4)));

#define DN_ 256
#define DE_ 64
#define DM_ 256
#define DX_ 256
#define LDH 136    // padded LDS stride (bf16) for K=128 half-tiles: 17408 B/block
#define LDA2 72    // padded LDS stride for K=64 tiles
#define CAP 32     // incoming-edge bucket capacity (Poisson mean 3; P(deg>32) ~ 1e-24)

// Workspace: base2 153.6 + msg/fnodeb(alias) 153.6 + cnt 0.4 + slot 12.8
//   + inv 1.2 + alpha3 5.12 + weights 0.56 + agg 51.2 = 378.5 MB (verified R2 plan).
// K=256 tiles are staged in TWO K=128 halves (LDS 17.4 KB vs 33.8 KB) so the
// occupancy limiter moves from LDS (4 blocks/CU) to VGPR (~6 blocks/CU).

static __device__ __forceinline__ bf16 f2b(float x) { return __float2bfloat16(x); }
static __device__ __forceinline__ float us2f(unsigned short u) {
    return __uint_as_float((unsigned)u << 16);
}

union U16x8 { uint4 u; unsigned short s[8]; };

static __device__ __forceinline__ f32x4 mfma16(bf16x8 a, bf16x8 b, f32x4 c) {
    return __builtin_amdgcn_mfma_f32_16x16x32_bf16(a, b, c, 0, 0, 0);
}

// 64xKLEN slab GEMM: acc += T(64xKLEN in LDS) @ WT (bf16, WT[n*WSTR + k], k in
// [0,KLEN) after caller pre-offsets WT by the k-origin). 4 waves: wave w owns
// cols [64w, 64w+64).
// SWAPPED operand order: mfma(b, a, acc) ->
//   value(lane, reg rr) = out[i*16 + (lane&15)][w*64 + j*16 + (lane>>4)*4 + rr]
// i.e. each lane holds 4 CONSECUTIVE COLUMNS of one row -> vectorized epilogues.
template <int LDA, int WSTR, int KLEN>
static __device__ __forceinline__ void gemm_acc(const bf16* T, const bf16* WT,
                                                f32x4 acc[4][4], int lane, int wave) {
    const int m = lane & 15, quad = lane >> 4;
#pragma unroll
    for (int k0 = 0; k0 < KLEN; k0 += 32) {
        bf16x8 a[4], b[4];
#pragma unroll
        for (int i = 0; i < 4; ++i)
            a[i] = *(const bf16x8*)&T[(i * 16 + m) * LDA + k0 + quad * 8];
#pragma unroll
        for (int j = 0; j < 4; ++j) {
            int n = wave * 64 + j * 16 + m;
            b[j] = *(const bf16x8*)&WT[(size_t)n * WSTR + k0 + quad * 8];
        }
#pragma unroll
        for (int i = 0; i < 4; ++i)
#pragma unroll
            for (int j = 0; j < 4; ++j)
                acc[i][j] = mfma16(b[j], a[i], acc[i][j]);
    }
}

// W (f32, K x NC row-major) -> WT (bf16, NC x K)
__global__ void __launch_bounds__(256) k_transpose(const float* __restrict__ W,
                                                   bf16* __restrict__ WT, int K, int NC) {
    int i = blockIdx.x * 256 + threadIdx.x;
    if (i < K * NC) {
        int k = i / NC, n = i % NC;
        WT[n * K + k] = f2b(W[i]);
    }
}

// f32 -> bf16 bulk convert (8 elems/thread)
__global__ void __launch_bounds__(256) k_cvt(const float* __restrict__ in,
                                             bf16* __restrict__ out, long total) {
    long i = ((long)blockIdx.x * 256 + threadIdx.x) * 8;
    if (i >= total) return;
    float4 v0 = *(const float4*)(in + i);
    float4 v1 = *(const float4*)(in + i + 4);
    bf16x8 b = {(__bf16)v0.x, (__bf16)v0.y, (__bf16)v0.z, (__bf16)v0.w,
                (__bf16)v1.x, (__bf16)v1.y, (__bf16)v1.z, (__bf16)v1.w};
    *(bf16x8*)(out + i) = b;
}

// incoming-edge buckets: slot[d*CAP + pos] = e for each e with edst[e]==d
__global__ void __launch_bounds__(256) k_bucket(const int* __restrict__ edst,
                                                int* __restrict__ cnt,
                                                int* __restrict__ slot, int E) {
    int e = blockIdx.x * 256 + threadIdx.x;
    if (e < E) {
        int d = edst[e];
        int pos = atomicAdd(&cnt[d], 1);
        if (pos < CAP) slot[(size_t)d * CAP + pos] = e;
    }
}

// inv[tgt[r]] = r  (inv pre-memset to -1)
__global__ void __launch_bounds__(256) k_invset(const int* __restrict__ tgt,
                                                int* __restrict__ inv, int M) {
    int r = blockIdx.x * 256 + threadIdx.x;
    if (r < M) inv[tgt[r]] = r;
}

// agg[n] = sum over incoming edges of msg rows (f32 accumulate, bf16 store).
// One wave per node; lane covers 4 cols. relu_in: treat input rows as relu(row)
// (used for virtual msg_1 = relu(base2)).
__global__ void __launch_bounds__(256) k_aggregate(const bf16* __restrict__ msg,
                                                   const int* __restrict__ cnt,
                                                   const int* __restrict__ slot,
                                                   bf16* __restrict__ agg, int N,
                                                   int relu_in) {
    int wid = (blockIdx.x * 256 + threadIdx.x) >> 6;  // node id
    int lane = threadIdx.x & 63;
    if (wid >= N) return;
    int c = cnt[wid];
    if (c > CAP) c = CAP;
    const int* sp = slot + (size_t)wid * CAP;
    float a0 = 0.f, a1 = 0.f, a2 = 0.f, a3 = 0.f;
    if (relu_in) {
        for (int i = 0; i < c; ++i) {
            int e = sp[i];
            ushort4 mv = *(const ushort4*)((const unsigned short*)msg + (size_t)e * DM_ + lane * 4);
            a0 += fmaxf(us2f(mv.x), 0.f); a1 += fmaxf(us2f(mv.y), 0.f);
            a2 += fmaxf(us2f(mv.z), 0.f); a3 += fmaxf(us2f(mv.w), 0.f);
        }
    } else {
        for (int i = 0; i < c; ++i) {
            int e = sp[i];
            ushort4 mv = *(const ushort4*)((const unsigned short*)msg + (size_t)e * DM_ + lane * 4);
            a0 += us2f(mv.x); a1 += us2f(mv.y); a2 += us2f(mv.z); a3 += us2f(mv.w);
        }
    }
    bf16x4 o = {(__bf16)a0, (__bf16)a1, (__bf16)a2, (__bf16)a3};
    *(bf16x4*)(agg + (size_t)wid * DM_ + lane * 4) = o;
}

// alpha3[r] = tree_msg[r] @ W3   (compact [M, DM] bf16 output)
__global__ void __launch_bounds__(256) k_alpha(const float* __restrict__ tm,
                                               const bf16* __restrict__ W3T,
                                               bf16* __restrict__ alpha3, int M) {
    __shared__ bf16 T[64 * LDH];
    const int tile0 = blockIdx.x * 64, tid = threadIdx.x;
    const int lane = tid & 63, wave = tid >> 6;
    const int m = lane & 15, quad = lane >> 4;
    f32x4 acc[4][4];
#pragma unroll
    for (int i = 0; i < 4; ++i)
#pragma unroll
        for (int j = 0; j < 4; ++j) acc[i][j] = (f32x4){0.f, 0.f, 0.f, 0.f};
#pragma unroll
    for (int h = 0; h < 2; ++h) {
#pragma unroll
        for (int it = 0; it < 8; ++it) {
            int c = tid + it * 256;
            int r = c >> 5, cc = c & 31;
            int row = tile0 + r;
            if (row >= M) row = 0;
            float4 v = *(const float4*)(tm + (size_t)row * DM_ + h * 128 + cc * 4);
            bf16x4 b = {(__bf16)v.x, (__bf16)v.y, (__bf16)v.z, (__bf16)v.w};
            *(bf16x4*)&T[r * LDH + cc * 4] = b;
        }
        __syncthreads();
        gemm_acc<LDH, 256, 128>(T, W3T + h * 128, acc, lane, wave);
        __syncthreads();
    }
#pragma unroll
    for (int i = 0; i < 4; ++i) {
        int row = tile0 + i * 16 + m;
        if (row < M) {
            size_t rb = (size_t)row * DM_;
#pragma unroll
            for (int j = 0; j < 4; ++j) {
                int c0 = wave * 64 + j * 16 + quad * 4;
                bf16x4 o = {(__bf16)acc[i][j][0], (__bf16)acc[i][j][1],
                            (__bf16)acc[i][j][2], (__bf16)acc[i][j][3]};
                *(bf16x4*)(alpha3 + rb + c0) = o;
            }
        }
    }
}

// base2 = f_node_bf16[src] @ W1 + f_edge @ W2 + b1 (+ alpha3[inv[e]] where inv>=0)
__global__ void __launch_bounds__(256) k_base(const bf16* __restrict__ fnb,
                                              const float* __restrict__ fedge,
                                              const int* __restrict__ esrc,
                                              const bf16* __restrict__ W1T,
                                              const bf16* __restrict__ W2T,
                                              const float* __restrict__ b1,
                                              const int* __restrict__ inv,
                                              const bf16* __restrict__ alpha3,
                                              bf16* __restrict__ base2, int E) {
    __shared__ bf16 T[64 * LDH];
    const int tile0 = blockIdx.x * 64, tid = threadIdx.x;
    const int lane = tid & 63, wave = tid >> 6;
    const int m = lane & 15, quad = lane >> 4;
    f32x4 acc[4][4];
#pragma unroll
    for (int i = 0; i < 4; ++i)
#pragma unroll
        for (int j = 0; j < 4; ++j) acc[i][j] = (f32x4){0.f, 0.f, 0.f, 0.f};
    // gathered f_node rows in two K=128 halves: pure 16B copies
#pragma unroll
    for (int h = 0; h < 2; ++h) {
#pragma unroll
        for (int it = 0; it < 4; ++it) {
            int c = tid + it * 256;
            int r = c >> 4, cc = c & 15;
            int e = tile0 + r;
            if (e >= E) e = 0;
            int s = esrc[e];
            *(uint4*)&T[r * LDH + cc * 8] =
                *(const uint4*)((const unsigned short*)fnb + (size_t)s * DN_ + h * 128 + cc * 8);
        }
        __syncthreads();
        gemm_acc<LDH, 256, 128>(T, W1T + h * 128, acc, lane, wave);
        __syncthreads();
    }
    // stage contiguous f_edge rows (64 x 64, f32 -> bf16)
#pragma unroll
    for (int it = 0; it < 4; ++it) {
        int c = tid + it * 256;
        int r = c >> 4, cc = c & 15;
        int e = tile0 + r;
        if (e >= E) e = 0;
        float4 v = *(const float4*)(fedge + (size_t)e * DE_ + cc * 4);
        bf16x4 b = {(__bf16)v.x, (__bf16)v.y, (__bf16)v.z, (__bf16)v.w};
        *(bf16x4*)&T[r * LDA2 + cc * 4] = b;
    }
    __syncthreads();
    gemm_acc<LDA2, 64, 64>(T, W2T, acc, lane, wave);
    // vectorized epilogue: each lane owns 4 consecutive cols of row (i*16+m)
    float4 bj[4];
#pragma unroll
    for (int j = 0; j < 4; ++j)
        bj[j] = *(const float4*)&b1[wave * 64 + j * 16 + quad * 4];
#pragma unroll
    for (int i = 0; i < 4; ++i) {
        int e = tile0 + i * 16 + m;
        if (e < E) {
            int iv = inv[e];
            size_t rb = (size_t)e * DM_;
#pragma unroll
            for (int j = 0; j < 4; ++j) {
                int c0 = wave * 64 + j * 16 + quad * 4;
                float v0 = acc[i][j][0] + bj[j].x;
                float v1 = acc[i][j][1] + bj[j].y;
                float v2 = acc[i][j][2] + bj[j].z;
                float v3 = acc[i][j][3] + bj[j].w;
                if (iv >= 0) {
                    ushort4 al = *(const ushort4*)((const unsigned short*)alpha3 +
                                                   (size_t)iv * DM_ + c0);
                    v0 += us2f(al.x); v1 += us2f(al.y);
                    v2 += us2f(al.z); v3 += us2f(al.w);
                }
                bf16x4 o = {(__bf16)v0, (__bf16)v1, (__bf16)v2, (__bf16)v3};
                *(bf16x4*)(base2 + rb + c0) = o;
            }
        }
    }
}

// msgout = relu(base2 + (agg[src] - msgin[rev]) @ W3)
// relu_in: msgin rows are raw base2 -> apply relu when reading (virtual msg_1).
__global__ void __launch_bounds__(256) k_update(const bf16* __restrict__ agg,
                                                const bf16* __restrict__ base2,
                                                const int* __restrict__ esrc,
                                                const bf16* __restrict__ W3T,
                                                const bf16* __restrict__ msgin,
                                                bf16* __restrict__ msgout, int E,
                                                int relu_in) {
    __shared__ bf16 T[64 * LDH];
    const int tile0 = blockIdx.x * 64, tid = threadIdx.x;
    const int lane = tid & 63, wave = tid >> 6;
    const int m = lane & 15, quad = lane >> 4;
    f32x4 acc[4][4];
#pragma unroll
    for (int i = 0; i < 4; ++i)
#pragma unroll
        for (int j = 0; j < 4; ++j) acc[i][j] = (f32x4){0.f, 0.f, 0.f, 0.f};
#pragma unroll
    for (int h = 0; h < 2; ++h) {
#pragma unroll
        for (int it = 0; it < 4; ++it) {
            int c = tid + it * 256;
            int r = c >> 4, cc = c & 15;
            int e = tile0 + r;
            int ec = e < E ? e : 0;
            int s = esrc[ec];
            int erev = tile0 + (r ^ 1);
            if (erev >= E) erev = 0;
            U16x8 av, mv;
            av.u = *(const uint4*)((const unsigned short*)agg +
                                   (size_t)s * DM_ + h * 128 + cc * 8);
            mv.u = *(const uint4*)((const unsigned short*)msgin +
                                   (size_t)erev * DM_ + h * 128 + cc * 8);
            bf16x8 o;
#pragma unroll
            for (int t = 0; t < 8; ++t) {
                float fm = us2f(mv.s[t]);
                if (relu_in) fm = fmaxf(fm, 0.f);
                o[t] = (__bf16)(us2f(av.s[t]) - fm);
            }
            *(bf16x8*)&T[r * LDH + cc * 8] = o;
        }
        __syncthreads();
        gemm_acc<LDH, 256, 128>(T, W3T + h * 128, acc, lane, wave);
        __syncthreads();
    }
#pragma unroll
    for (int i = 0; i < 4; ++i) {
        int e = tile0 + i * 16 + m;
        if (e < E) {
            size_t rb = (size_t)e * DM_;
#pragma unroll
            for (int j = 0; j < 4; ++j) {
                int c0 = wave * 64 + j * 16 + quad * 4;
                ushort4 bv = *(const ushort4*)((const unsigned short*)base2 + rb + c0);
                float v0 = fmaxf(acc[i][j][0] + us2f(bv.x), 0.f);
                float v1 = fmaxf(acc[i][j][1] + us2f(bv.y), 0.f);
                float v2 = fmaxf(acc[i][j][2] + us2f(bv.z), 0.f);
                float v3 = fmaxf(acc[i][j][3] + us2f(bv.w), 0.f);
                bf16x4 o = {(__bf16)v0, (__bf16)v1, (__bf16)v2, (__bf16)v3};
                *(bf16x4*)(msgout + rb + c0) = o;
            }
        }
    }
}

// x = relu(f_node @ W4 + agg @ W5 + b2)   (f32 output, float4 stores)
__global__ void __launch_bounds__(256) k_readout(const float* __restrict__ fnode,
                                                 const bf16* __restrict__ agg,
                                                 const bf16* __restrict__ W4T,
                                                 const bf16* __restrict__ W5T,
                                                 const float* __restrict__ b2,
                                                 float* __restrict__ out, int N) {
    __shared__ bf16 T[64 * LDH];
    const int tile0 = blockIdx.x * 64, tid = threadIdx.x;
    const int lane = tid & 63, wave = tid >> 6;
    const int m = lane & 15, quad = lane >> 4;
    f32x4 acc[4][4];
#pragma unroll
    for (int i = 0; i < 4; ++i)
#pragma unroll
        for (int j = 0; j < 4; ++j) acc[i][j] = (f32x4){0.f, 0.f, 0.f, 0.f};
    // f_node (f32) in two K=128 halves
#pragma unroll
    for (int h = 0; h < 2; ++h) {
#pragma unroll
        for (int it = 0; it < 8; ++it) {
            int c = tid + it * 256;
            int r = c >> 5, cc = c & 31;
            int n = tile0 + r;
            if (n >= N) n = 0;
            float4 v = *(const float4*)(fnode + (size_t)n * DN_ + h * 128 + cc * 4);
            bf16x4 b = {(__bf16)v.x, (__bf16)v.y, (__bf16)v.z, (__bf16)v.w};
            *(bf16x4*)&T[r * LDH + cc * 4] = b;
        }
        __syncthreads();
        gemm_acc<LDH, 256, 128>(T, W4T + h * 128, acc, lane, wave);
        __syncthreads();
    }
    // agg rows (already bf16) in two K=128 halves: 16B copies
#pragma unroll
    for (int h = 0; h < 2; ++h) {
#pragma unroll
        for (int it = 0; it < 4; ++it) {
            int c = tid + it * 256;
            int r = c >> 4, cc = c & 15;
            int n = tile0 + r;
            if (n >= N) n = 0;
            *(uint4*)&T[r * LDH + cc * 8] =
                *(const uint4*)((const unsigned short*)agg + (size_t)n * DM_ + h * 128 + cc * 8);
        }
        __syncthreads();
        gemm_acc<LDH, 256, 128>(T, W5T + h * 128, acc, lane, wave);
        __syncthreads();
    }
    float4 bj[4];
#pragma unroll
    for (int j = 0; j < 4; ++j)
        bj[j] = *(const float4*)&b2[wave * 64 + j * 16 + quad * 4];
#pragma unroll
    for (int i = 0; i < 4; ++i) {
        int n = tile0 + i * 16 + m;
        if (n < N) {
            size_t rb = (size_t)n * DX_;
#pragma unroll
            for (int j = 0; j < 4; ++j) {
                int c0 = wave * 64 + j * 16 + quad * 4;
                float4 o;
                o.x = fmaxf(acc[i][j][0] + bj[j].x, 0.f);
                o.y = fmaxf(acc[i][j][1] + bj[j].y, 0.f);
                o.z = fmaxf(acc[i][j][2] + bj[j].z, 0.f);
                o.w = fmaxf(acc[i][j][3] + bj[j].w, 0.f);
                *(float4*)(out + rb + c0) = o;
            }
        }
    }
}

extern "C" void kernel_launch(void* const* d_in, const int* in_sizes, int n_in,
                              void* d_out, int out_size, void* d_ws, size_t ws_size,
                              hipStream_t stream) {
    const float* f_node   = (const float*)d_in[0];
    const float* f_edge   = (const float*)d_in[1];
    const float* tree_msg = (const float*)d_in[2];
    const float* W1 = (const float*)d_in[3];
    const float* W2 = (const float*)d_in[4];
    const float* W3 = (const float*)d_in[5];
    const float* b1 = (const float*)d_in[6];
    const float* W4 = (const float*)d_in[7];
    const float* W5 = (const float*)d_in[8];
    const float* b2 = (const float*)d_in[9];
    const int* edge_src = (const int*)d_in[10];
    const int* edge_dst = (const int*)d_in[11];
    const int* tree_tgt = (const int*)d_in[12];

    const int N = in_sizes[0] / DN_;
    const int E = in_sizes[1] / DE_;
    const int M = in_sizes[2] / DM_;

    char* ws = (char*)d_ws;
    size_t off = 0;
    bf16* base2 = (bf16*)(ws + off); off += (size_t)E * DM_ * 2;
    bf16* msg   = (bf16*)(ws + off); off += (size_t)E * DM_ * 2;
    bf16* agg   = (bf16*)(ws + off); off += (size_t)N * DM_ * 2;
    int* cnt    = (int*)(ws + off);   off += (size_t)N * 4;
    int* slot   = (int*)(ws + off);   off += (size_t)N * CAP * 4;
    int* inv    = (int*)(ws + off);   off += (size_t)E * 4;
    bf16* alpha3 = (bf16*)(ws + off); off += (size_t)M * DM_ * 2;
    bf16* W1T = (bf16*)(ws + off); off += 256 * 256 * 2;
    bf16* W2T = (bf16*)(ws + off); off += 256 * 64 * 2;
    bf16* W3T = (bf16*)(ws + off); off += 256 * 256 * 2;
    bf16* W4T = (bf16*)(ws + off); off += 256 * 256 * 2;
    bf16* W5T = (bf16*)(ws + off); off += 256 * 256 * 2;
    bf16* fnb = msg;  // alias: f_node bf16 lives in msg buffer until msg first write

    k_transpose<<<(256 * 256 + 255) / 256, 256, 0, stream>>>(W1, W1T, 256, 256);
    k_transpose<<<(64 * 256 + 255) / 256, 256, 0, stream>>>(W2, W2T, 64, 256);
    k_transpose<<<(256 * 256 + 255) / 256, 256, 0, stream>>>(W3, W3T, 256, 256);
    k_transpose<<<(256 * 256 + 255) / 256, 256, 0, stream>>>(W4, W4T, 256, 256);
    k_transpose<<<(256 * 256 + 255) / 256, 256, 0, stream>>>(W5, W5T, 256, 256);

    // one-time CSR-bucket + inverse-alpha map for the (static) graph
    hipMemsetAsync(cnt, 0, (size_t)N * 4, stream);
    hipMemsetAsync(inv, 0xFF, (size_t)E * 4, stream);
    k_bucket<<<(E + 255) / 256, 256, 0, stream>>>(edge_dst, cnt, slot, E);
    k_invset<<<(M + 255) / 256, 256, 0, stream>>>(tree_tgt, inv, M);

    // bf16 copy of f_node (into msg alias) for the edge gather
    k_cvt<<<(int)(((size_t)N * DN_ / 8 + 255) / 256), 256, 0, stream>>>(
        f_node, fnb, (long)N * DN_);

    k_alpha<<<(M + 63) / 64, 256, 0, stream>>>(tree_msg, W3T, alpha3, M);
    k_base<<<(E + 63) / 64, 256, 0, stream>>>(fnb, f_edge, edge_src, W1T, W2T, b1,
                                              inv, alpha3, base2, E);
    // ITERS=3; msg_1 = relu(base2) is virtual (relu_in=1 readers), never materialized
    k_aggregate<<<(N + 3) / 4, 256, 0, stream>>>(base2, cnt, slot, agg, N, 1);
    k_update<<<(E + 63) / 64, 256, 0, stream>>>(agg, base2, edge_src, W3T,
                                                base2, msg, E, 1);
    k_aggregate<<<(N + 3) / 4, 256, 0, stream>>>(msg, cnt, slot, agg, N, 0);
    k_update<<<(E + 63) / 64, 256, 0, stream>>>(agg, base2, edge_src, W3T,
                                                msg, msg, E, 0);
    k_aggregate<<<(N + 3) / 4, 256, 0, stream>>>(msg, cnt, slot, agg, N, 0);
    k_readout<<<(N + 63) / 64, 256, 0, stream>>>(f_node, agg, W4T, W5T, b2,
                                                 (float*)d_out, N);
}